// Round 7
// baseline (59.649 us; speedup 1.0000x reference)
//
#include <hip/hip_runtime.h>

#define DENSE_L 20
#define LT 16
#define BLOCK 256
#define KQ 4                   // k-outputs per quarter
#define GPP (DENSE_L * KQ)     // 80 G floats per quarter = 5 x 64B uniform loads

typedef float v4f  __attribute__((ext_vector_type(4)));
typedef float v16f __attribute__((ext_vector_type(16)));

// Precompute G transposed: Gt[k*20 + t] = exp(-((t+1)-w_k)^2 / std^2).
__global__ void g_precompute(const float* __restrict__ weight, float* __restrict__ Gt)
{
    int i = threadIdx.x;               // 320 threads
    if (i < DENSE_L * LT) {
        int k = i / DENSE_L;
        int t = i - k * DENSE_L;
        float d = (float)(t + 1) - weight[k];
        Gt[i] = __expf(-d * d * 6.25f);    // 1/std^2 = 6.25
    }
}

// R6 evidence: SGPR-G + bulk-x is right (FETCH 42MB, SGPR 96, 0 LDS) but
// per-pass 16B stores amplified writes (87 vs 66MB) and RPT=2 kept the
// per-thread latency chain long. R7: RPT=1 (live ~50 VGPR -> 8 waves/SIMD),
// full acc[16] with ONE 64B store/row, G k-quarters fully unrolled with
// memory fences so only 80 G SGPRs are live at a time (hipcc hoists
// uniform loads otherwise -> SGPR cap blown, R0/R3 failure mode).
#define QUARTER(P)                                                          \
    {                                                                       \
        const v16f* gq = reinterpret_cast<const v16f*>(Gt + (P) * GPP);     \
        v16f q[5] = {gq[0], gq[1], gq[2], gq[3], gq[4]};                    \
        _Pragma("unroll")                                                   \
        for (int kk = 0; kk < KQ; ++kk) {                                   \
            _Pragma("unroll")                                               \
            for (int t = 0; t < DENSE_L; ++t) {                             \
                int gi = kk * DENSE_L + t;       /* compile-time */         \
                acc[(P) * KQ + kk] += xv[t] * q[gi >> 4][gi & 15];          \
            }                                                               \
        }                                                                   \
    }

__global__ __launch_bounds__(BLOCK) void sampling_kernel(
    const float* __restrict__ x, const float* __restrict__ Gt,
    float* __restrict__ out, int nrows)
{
    int row = blockIdx.x * BLOCK + threadIdx.x;
    if (row >= nrows) return;          // grid divides exactly (1M/256); cheap guard

    // Bulk load the row: 5 float4 back-to-back (one tight window per line,
    // max MLP — the R0/R6-proven pattern; chunked streaming re-fetched HBM).
    float xv[DENSE_L];
    const float4* p = reinterpret_cast<const float4*>(x + (size_t)row * DENSE_L);
    #pragma unroll
    for (int j = 0; j < DENSE_L / 4; ++j) {
        float4 v = p[j];
        xv[4*j+0] = v.x; xv[4*j+1] = v.y; xv[4*j+2] = v.z; xv[4*j+3] = v.w;
    }

    float acc[LT];
    #pragma unroll
    for (int k = 0; k < LT; ++k) acc[k] = 0.f;

    QUARTER(0)
    asm volatile("" ::: "memory");     // fence: keep quarter SGPR live-ranges disjoint
    QUARTER(1)
    asm volatile("" ::: "memory");
    QUARTER(2)
    asm volatile("" ::: "memory");
    QUARTER(3)

    // One contiguous 64B store per row (fixes R6's 30% write amplification).
    // Non-temporal: out is never re-read; keep L2/L3 for x (x L3-fits at 84MB).
    v4f* o = reinterpret_cast<v4f*>(out + (size_t)row * LT);
    __builtin_nontemporal_store((v4f){acc[0],  acc[1],  acc[2],  acc[3]},  o + 0);
    __builtin_nontemporal_store((v4f){acc[4],  acc[5],  acc[6],  acc[7]},  o + 1);
    __builtin_nontemporal_store((v4f){acc[8],  acc[9],  acc[10], acc[11]}, o + 2);
    __builtin_nontemporal_store((v4f){acc[12], acc[13], acc[14], acc[15]}, o + 3);
}

extern "C" void kernel_launch(void* const* d_in, const int* in_sizes, int n_in,
                              void* d_out, int out_size, void* d_ws, size_t ws_size,
                              hipStream_t stream) {
    const float* x = (const float*)d_in[0];
    const float* w = (const float*)d_in[1];
    float* out = (float*)d_out;
    float* Gt = (float*)d_ws;                // 320 floats = 1280 B workspace
    int nrows = in_sizes[0] / DENSE_L;       // 1,048,576

    g_precompute<<<1, 320, 0, stream>>>(w, Gt);

    int grid = (nrows + BLOCK - 1) / BLOCK;  // 4096 blocks
    sampling_kernel<<<grid, BLOCK, 0, stream>>>(x, Gt, out, nrows);
}

// Round 8
// 35.488 us; speedup vs baseline: 1.6808x; 1.6808x over previous
//
#include <hip/hip_runtime.h>

#define DENSE_L 20
#define LT 16
#define BLOCK 256
#define KQ 4                   // k-outputs per quarter pass
#define NPASS (LT / KQ)        // 4
#define GPP (DENSE_L * KQ)     // 80 G floats per pass = 5 x 64B uniform loads
#define OPAD 20                // padded out-stage row (dwords): 2-way banks, 16B-aligned

typedef float v4f  __attribute__((ext_vector_type(4)));
typedef float v16f __attribute__((ext_vector_type(16)));

// Precompute G transposed: Gt[k*20 + t] = exp(-((t+1)-w_k)^2 / std^2).
__global__ void g_precompute(const float* __restrict__ weight, float* __restrict__ Gt)
{
    int i = threadIdx.x;               // 320 threads
    if (i < DENSE_L * LT) {
        int k = i / DENSE_L;
        int t = i - k * DENSE_L;
        float d = (float)(t + 1) - weight[k];
        Gt[i] = __expf(-d * d * 6.25f);    // 1/std^2 = 6.25
    }
}

// R0-R7 synthesis: occupancy 8->56% never moved the ~50us floor; the limiter is
// the 80B-strided per-lane x access (64 line-probes per vector load, miss-queue
// bound). R8: stage x through LDS with perfectly coalesced global loads, read
// rows from LDS (80B stride = 2-way banks = free). Keep R6's PROVEN rolled
// SGPR-G quarters (no fences - R7 lesson). Stage out in LDS, store coalesced
// full lines (fixes R6 write-amp; regular stores - NT amplified 1.8x R4/R7).
__global__ __launch_bounds__(BLOCK) void sampling_kernel(
    const float* __restrict__ x, const float* __restrict__ Gt,
    float* __restrict__ out, int nrows)
{
    __shared__ float lds[BLOCK * DENSE_L];   // 20 KB: x stage, then out stage

    const int tid = threadIdx.x;
    const size_t blockRow = (size_t)blockIdx.x * BLOCK;

    // ---- coalesced x load: 1280 float4s, lane i -> float4 i (+256j) ----
    {
        const float4* px = reinterpret_cast<const float4*>(x + blockRow * DENSE_L);
        #pragma unroll
        for (int j = 0; j < 5; ++j) {
            int f = tid + BLOCK * j;                 // float4 index in block tile
            float4 v = px[f];
            *reinterpret_cast<float4*>(&lds[4 * f]) = v;   // linear LDS, 16B aligned
        }
    }
    __syncthreads();

    // ---- each thread pulls its own row from LDS (5 x ds_read_b128, 2-way) ----
    float xv[DENSE_L];
    {
        #pragma unroll
        for (int j = 0; j < 5; ++j) {
            float4 v = *reinterpret_cast<const float4*>(&lds[tid * DENSE_L + 4 * j]);
            xv[4*j+0] = v.x; xv[4*j+1] = v.y; xv[4*j+2] = v.z; xv[4*j+3] = v.w;
        }
    }
    __syncthreads();   // all row-reads done before out-stage overwrites lds

    // ---- 4 rolled k-quarter passes; G uniform-loaded into SGPRs (R6-proven) ----
    #pragma unroll 1
    for (int p = 0; p < NPASS; ++p) {
        const v16f* gq = reinterpret_cast<const v16f*>(Gt + p * GPP);
        v16f q[5] = {gq[0], gq[1], gq[2], gq[3], gq[4]};

        float a[KQ] = {0.f, 0.f, 0.f, 0.f};
        #pragma unroll
        for (int kk = 0; kk < KQ; ++kk) {
            #pragma unroll
            for (int t = 0; t < DENSE_L; ++t) {
                int gi = kk * DENSE_L + t;            // compile-time after unroll
                a[kk] += xv[t] * q[gi >> 4][gi & 15]; // v_fmac v,s,v
            }
        }
        // stage quarter into LDS: row tid, padded stride 20 dwords (2-way banks)
        *reinterpret_cast<v4f*>(&lds[tid * OPAD + 4 * p]) = (v4f){a[0], a[1], a[2], a[3]};
    }
    __syncthreads();

    // ---- coalesced out store: full 64B lines, regular stores ----
    {
        float4* po = reinterpret_cast<float4*>(out + blockRow * LT);
        #pragma unroll
        for (int j = 0; j < 4; ++j) {
            int g = tid + BLOCK * j;                 // global float4 index in tile
            int r = g >> 2, s = g & 3;               // out row / sub-quad
            float4 v = *reinterpret_cast<const float4*>(&lds[r * OPAD + 4 * s]);
            po[g] = v;
        }
    }
}

extern "C" void kernel_launch(void* const* d_in, const int* in_sizes, int n_in,
                              void* d_out, int out_size, void* d_ws, size_t ws_size,
                              hipStream_t stream) {
    const float* x = (const float*)d_in[0];
    const float* w = (const float*)d_in[1];
    float* out = (float*)d_out;
    float* Gt = (float*)d_ws;                // 320 floats = 1280 B workspace
    int nrows = in_sizes[0] / DENSE_L;       // 1,048,576 (divisible by 256)

    g_precompute<<<1, 320, 0, stream>>>(w, Gt);

    int grid = nrows / BLOCK;                // 4096 full blocks
    sampling_kernel<<<grid, BLOCK, 0, stream>>>(x, Gt, out, nrows);
}